// Round 8
// baseline (367.612 us; speedup 1.0000x reference)
//
#include <hip/hip_runtime.h>
#include <hip/hip_bf16.h>

#define VIS_DIM 2048
#define TXT_DIM 1024
#define HID     1024
#define NB      128          // batch
#define NR      256          // regions
#define M_TOT   (NB*NR)      // 32768

typedef __attribute__((ext_vector_type(4))) float  f32x4;
typedef __attribute__((ext_vector_type(8))) short  short8;   // 8 x bf16 (4 VGPR)
typedef __attribute__((ext_vector_type(4))) unsigned short u16x4;

static __device__ __forceinline__ unsigned short f2bf(float f) {
    union { __hip_bfloat16 h; unsigned short u; } c;
    c.h = __float2bfloat16(f);
    return c.u;
}

static __device__ __forceinline__ float tanh_fast(float x) {
    float xc = fminf(fmaxf(x, -15.f), 15.f);
    float e  = __expf(2.f * xc);
    return (e - 1.f) / (e + 1.f);
}

// ---------------------------------------------------------------------------
// init: zero scores, t = bt broadcast (atomics accumulate on top)
// ---------------------------------------------------------------------------
__global__ void init_ws(float* __restrict__ scores, float* __restrict__ tbuf,
                        const float* __restrict__ bt) {
    int i = blockIdx.x * 256 + threadIdx.x;        // grid covers 131072
    if (i < M_TOT) scores[i] = 0.f;
    tbuf[i] = bt[i & (HID - 1)];
}

// ---------------------------------------------------------------------------
// t = text @ Wt^T (+bt already in tbuf). Split-K fp32 tiled GEMM, atomicAdd.
// ---------------------------------------------------------------------------
__global__ __launch_bounds__(256) void gemm_text(const float* __restrict__ text,
                                                 const float* __restrict__ Wt,
                                                 float* __restrict__ tbuf) {
    __shared__ float As[128][33];
    __shared__ float Bs[32][33];
    const int n0  = blockIdx.x * 32;
    const int k0  = blockIdx.y * 256;
    const int tid = threadIdx.x;
    const int tm  = tid >> 3;
    const int tn  = tid & 7;
    float acc[4][4] = {};
    for (int kt = 0; kt < 8; ++kt) {
        const int k = k0 + kt * 32;
        {   // stage A: 128x32
            int row = tid >> 1, off = (tid & 1) * 16;
            const float* src = text + row * TXT_DIM + k + off;
            #pragma unroll
            for (int j = 0; j < 4; ++j) {
                f32x4 v = *(const f32x4*)(src + j * 4);
                As[row][off + j*4 + 0] = v.x; As[row][off + j*4 + 1] = v.y;
                As[row][off + j*4 + 2] = v.z; As[row][off + j*4 + 3] = v.w;
            }
        }
        {   // stage B: 32x32
            int row = tid >> 3, off = (tid & 7) * 4;
            f32x4 v = *(const f32x4*)(Wt + (size_t)(n0 + row) * TXT_DIM + k + off);
            Bs[row][off + 0] = v.x; Bs[row][off + 1] = v.y;
            Bs[row][off + 2] = v.z; Bs[row][off + 3] = v.w;
        }
        __syncthreads();
        #pragma unroll
        for (int kk = 0; kk < 32; ++kk) {
            float a[4], b[4];
            #pragma unroll
            for (int i = 0; i < 4; ++i) a[i] = As[tm*4 + i][kk];
            #pragma unroll
            for (int j = 0; j < 4; ++j) b[j] = Bs[tn*4 + j][kk];
            #pragma unroll
            for (int i = 0; i < 4; ++i)
                #pragma unroll
                for (int j = 0; j < 4; ++j) acc[i][j] += a[i] * b[j];
        }
        __syncthreads();
    }
    #pragma unroll
    for (int i = 0; i < 4; ++i)
        #pragma unroll
        for (int j = 0; j < 4; ++j)
            atomicAdd(&tbuf[(tm*4 + i) * HID + n0 + tn*4 + j], acc[i][j]);
}

// ---------------------------------------------------------------------------
// Main fused GEMM: scores[row] += sum_col Wa[col]*tanh(A@Wv^T + bv + t)
// R8 = R5 structure (best measured: depth-2, two asm stage sets, vmcnt(8))
// + NEW BLOCK MAPPING: nb = wg&7, mb = wg>>3 (identity, n-fastest).
// HW round-robin puts wg on XCD wg%8 = nb -> each XCD owns ONE 1MB B-column
// panel (L2-resident forever), and the 8 nb-siblings of each mb run
// SIMULTANEOUSLY across the 8 XCDs -> A-panel read 8x within a tight window,
// L3 serves 7/8. R5-R7's mapping had 8MB A + 8MB B cycling per 4MB L2 ->
// FETCH 620MB vs 264MB ideal; kernel ran exactly at achieved BW.
// ---------------------------------------------------------------------------
#define BK 32
#define NT (VIS_DIM / BK)    // 64

// byte offset inside one 8 KB bf16 tile [128 rows][32 k], 16B-slot swizzled
// (row stride 64 B: row bit0 is addr bit6, so XOR uses (row>>1)&3)
static __device__ __forceinline__ int tile_off(int row, int kElem) {
    return row * 64 + (((kElem >> 3) ^ ((row >> 1) & 3)) << 4);
}

__global__ __launch_bounds__(256, 2) void gemm_vis(
        const float* __restrict__ A,     // visual  32768 x 2048
        const float* __restrict__ Bv,    // Wv      1024 x 2048
        const float* __restrict__ bv,
        const float* __restrict__ wa,    // Wa[0]   1024
        const float* __restrict__ tbuf,  // 128 x 1024
        float* __restrict__ scores) {
    __shared__ __align__(16) char lds[32768];   // 2 buf x (A 8KB + B 8KB)

    // Identity mapping; see header comment. 2048 blocks = 256 mb x 8 nb.
    const int wg   = blockIdx.x;
    const int nb   = wg & 7;    // == XCD id under HW round-robin
    const int mb   = wg >> 3;
    const int brow = mb * 128;
    const int bcol = nb * 128;

    const int tid  = threadIdx.x;
    const int lane = tid & 63;
    const int wid  = tid >> 6;
    const int wr   = wid >> 1, wc = wid & 1;   // 2x2 waves of 64x64

    // staging map: load r (0..3): row = (tid>>3)+32r, sfs = tid&7 (f32x4 slot)
    const int srow = tid >> 3;
    const int sfs  = tid & 7;
    // 32-bit byte voffsets into A / Bv (max 256 MB / 8 MB: fits u32)
    unsigned va0 = ((unsigned)(brow + srow      ) * VIS_DIM + sfs * 4) * 4u;
    unsigned va1 = va0 + 32u * VIS_DIM * 4u;
    unsigned va2 = va0 + 64u * VIS_DIM * 4u;
    unsigned va3 = va0 + 96u * VIS_DIM * 4u;
    unsigned vb0 = ((unsigned)(bcol + srow      ) * VIS_DIM + sfs * 4) * 4u;
    unsigned vb1 = vb0 + 32u * VIS_DIM * 4u;
    unsigned vb2 = vb0 + 64u * VIS_DIM * 4u;
    unsigned vb3 = vb0 + 96u * VIS_DIM * 4u;

    // LDS write byte offsets (within a tile) per r: 8B granule, swizzled
    int wbyte[4];
    #pragma unroll
    for (int r = 0; r < 4; ++r) {
        int row = srow + 32 * r;
        wbyte[r] = row * 64 + (((sfs >> 1) ^ ((row >> 1) & 3)) << 4) + (sfs & 1) * 8;
    }

    // Two stage sets: S (even tiles' loader) and T (odd tiles' loader).
    f32x4 sA0, sA1, sA2, sA3, sB0, sB1, sB2, sB3;
    f32x4 tA0, tA1, tA2, tA3, tB0, tB1, tB2, tB3;
    f32x4 acc[4][4] = {};

    // Issue 8 loads into a named set (volatile asm: pinned, un-spillable,
    // un-sinkable) and advance the shared offsets by one tile (128 B).
#define GLOAD_SET(dA0,dA1,dA2,dA3,dB0,dB1,dB2,dB3)                             \
    do {                                                                       \
        asm volatile("global_load_dwordx4 %0, %1, %2"                          \
                     : "=&v"(dA0) : "v"(va0), "s"(A) : "memory");              \
        asm volatile("global_load_dwordx4 %0, %1, %2"                          \
                     : "=&v"(dA1) : "v"(va1), "s"(A) : "memory");              \
        asm volatile("global_load_dwordx4 %0, %1, %2"                          \
                     : "=&v"(dA2) : "v"(va2), "s"(A) : "memory");              \
        asm volatile("global_load_dwordx4 %0, %1, %2"                          \
                     : "=&v"(dA3) : "v"(va3), "s"(A) : "memory");              \
        asm volatile("global_load_dwordx4 %0, %1, %2"                          \
                     : "=&v"(dB0) : "v"(vb0), "s"(Bv) : "memory");             \
        asm volatile("global_load_dwordx4 %0, %1, %2"                          \
                     : "=&v"(dB1) : "v"(vb1), "s"(Bv) : "memory");             \
        asm volatile("global_load_dwordx4 %0, %1, %2"                          \
                     : "=&v"(dB2) : "v"(vb2), "s"(Bv) : "memory");             \
        asm volatile("global_load_dwordx4 %0, %1, %2"                          \
                     : "=&v"(dB3) : "v"(vb3), "s"(Bv) : "memory");             \
        va0 += BK * 4; va1 += BK * 4; va2 += BK * 4; va3 += BK * 4;            \
        vb0 += BK * 4; vb1 += BK * 4; vb2 += BK * 4; vb3 += BK * 4;            \
    } while (0)

#define GLOAD_S() GLOAD_SET(sA0,sA1,sA2,sA3,sB0,sB1,sB2,sB3)
#define GLOAD_T() GLOAD_SET(tA0,tA1,tA2,tA3,tB0,tB1,tB2,tB3)

    // Counted wait: keep N newest loads in flight; fence compiler motion
    // (rule #18: register-only ops can hoist past asm waitcnt without the
    // sched_barrier pair).
#define VWAIT(N)                                                               \
    do {                                                                       \
        __builtin_amdgcn_sched_barrier(0);                                     \
        asm volatile("s_waitcnt vmcnt(" #N ")" ::: "memory");                  \
        __builtin_amdgcn_sched_barrier(0);                                     \
    } while (0)

#define CVT8(dst, v0)                                                          \
    do {                                                                       \
        u16x4 t_;                                                              \
        t_.x = f2bf((v0).x); t_.y = f2bf((v0).y);                              \
        t_.z = f2bf((v0).z); t_.w = f2bf((v0).w);                              \
        dst = t_;                                                              \
    } while (0)

#define LWRITE_SET(bufbase, dA0,dA1,dA2,dA3,dB0,dB1,dB2,dB3)                   \
    do {                                                                       \
        u16x4 w_;                                                              \
        char* la = lds + (bufbase);                                            \
        char* lb = lds + (bufbase) + 8192;                                     \
        CVT8(w_, dA0); *(u16x4*)(la + wbyte[0]) = w_;                          \
        CVT8(w_, dA1); *(u16x4*)(la + wbyte[1]) = w_;                          \
        CVT8(w_, dA2); *(u16x4*)(la + wbyte[2]) = w_;                          \
        CVT8(w_, dA3); *(u16x4*)(la + wbyte[3]) = w_;                          \
        CVT8(w_, dB0); *(u16x4*)(lb + wbyte[0]) = w_;                          \
        CVT8(w_, dB1); *(u16x4*)(lb + wbyte[1]) = w_;                          \
        CVT8(w_, dB2); *(u16x4*)(lb + wbyte[2]) = w_;                          \
        CVT8(w_, dB3); *(u16x4*)(lb + wbyte[3]) = w_;                          \
    } while (0)

#define LWRITE_S(bufbase) LWRITE_SET(bufbase, sA0,sA1,sA2,sA3,sB0,sB1,sB2,sB3)
#define LWRITE_T(bufbase) LWRITE_SET(bufbase, tA0,tA1,tA2,tA3,tB0,tB1,tB2,tB3)

#define COMPUTE(bufbase)                                                       \
    do {                                                                       \
        short8 af[4], bf[4];                                                   \
        const int kk = (lane >> 4) * 8;                                        \
        const char* la = lds + (bufbase);                                      \
        const char* lb = lds + (bufbase) + 8192;                               \
        _Pragma("unroll")                                                      \
        for (int m = 0; m < 4; ++m)                                            \
            af[m] = *(const short8*)(la + tile_off(wr*64 + m*16 + (lane&15), kk)); \
        _Pragma("unroll")                                                      \
        for (int n = 0; n < 4; ++n)                                            \
            bf[n] = *(const short8*)(lb + tile_off(wc*64 + n*16 + (lane&15), kk)); \
        _Pragma("unroll")                                                      \
        for (int m = 0; m < 4; ++m)                                            \
            _Pragma("unroll")                                                  \
            for (int n = 0; n < 4; ++n)                                        \
                acc[m][n] = __builtin_amdgcn_mfma_f32_16x16x32_bf16(           \
                    af[m], bf[n], acc[m][n], 0, 0, 0);                         \
    } while (0)

    // Prologue: tiles 0 (S) and 1 (T) issued; stage tile 0 into buf0.
    GLOAD_S();                 // tile 0  (outstanding 8)
    GLOAD_T();                 // tile 1  (outstanding 16)
    VWAIT(8);                  // S ready; T in flight
    LWRITE_S(0);
    __syncthreads();

    // Steady state: invariant at iter-top = 8 outstanding (next tile's batch).
    #pragma unroll 1
    for (int kt = 0; kt < NT - 2; kt += 2) {
        // even tile kt: buf0 compute, prefetch kt+2 into S, stage kt+1 (T)->buf1
        GLOAD_S();             // tile kt+2 (outstanding 16)
        COMPUTE(0);
        VWAIT(8);              // T (tile kt+1) ready; S stays in flight
        LWRITE_T(16384);
        __syncthreads();
        // odd tile kt+1: buf1 compute, prefetch kt+3 into T, stage kt+2 (S)->buf0
        GLOAD_T();             // tile kt+3 (outstanding 16)
        COMPUTE(16384);
        VWAIT(8);              // S (tile kt+2) ready; T stays in flight
        LWRITE_S(0);
        __syncthreads();
    }
    // Epilogue: buf0 holds tile 62; T's batch (tile 63) still in flight.
    COMPUTE(0);
    VWAIT(0);
    LWRITE_T(16384);
    __syncthreads();
    COMPUTE(16384);
#undef GLOAD_SET
#undef GLOAD_S
#undef GLOAD_T
#undef VWAIT
#undef CVT8
#undef LWRITE_SET
#undef LWRITE_S
#undef LWRITE_T
#undef COMPUTE

    // ---- epilogue: tanh + Wa-dot, reduce over 16 cols/lane-group, atomicAdd
    const int b = brow >> 8;                 // batch index (tile fits in one b)
    float wa_c[4], bvt_c[4];
    #pragma unroll
    for (int n = 0; n < 4; ++n) {
        int col = bcol + wc * 64 + n * 16 + (lane & 15);
        wa_c[n]  = wa[col];
        bvt_c[n] = bv[col] + tbuf[b * HID + col];
    }
    #pragma unroll
    for (int m = 0; m < 4; ++m) {
        float p0 = 0.f, p1 = 0.f, p2 = 0.f, p3 = 0.f;
        #pragma unroll
        for (int n = 0; n < 4; ++n) {
            f32x4 v = acc[m][n];
            p0 += wa_c[n] * tanh_fast(v.x + bvt_c[n]);
            p1 += wa_c[n] * tanh_fast(v.y + bvt_c[n]);
            p2 += wa_c[n] * tanh_fast(v.z + bvt_c[n]);
            p3 += wa_c[n] * tanh_fast(v.w + bvt_c[n]);
        }
        #pragma unroll
        for (int d = 1; d < 16; d <<= 1) {
            p0 += __shfl_xor(p0, d); p1 += __shfl_xor(p1, d);
            p2 += __shfl_xor(p2, d); p3 += __shfl_xor(p3, d);
        }
        if ((lane & 15) == 0) {
            int rowg = brow + wr * 64 + m * 16 + (lane >> 4) * 4;
            atomicAdd(&scores[rowg + 0], p0);
            atomicAdd(&scores[rowg + 1], p1);
            atomicAdd(&scores[rowg + 2], p2);
            atomicAdd(&scores[rowg + 3], p3);
        }
    }
}

// ---------------------------------------------------------------------------
// softmax over regions + attended = w . visual ; grid (8 d-chunks, 128 b)
// ---------------------------------------------------------------------------
__global__ __launch_bounds__(256) void attend(const float* __restrict__ visual,
                                              const float* __restrict__ scores,
                                              float* __restrict__ out) {
    const int chunk = blockIdx.x;   // 0..7 -> 256 d each
    const int b     = blockIdx.y;   // 0..127
    const int tid   = threadIdx.x;
    const int lane  = tid & 63;
    const int wv    = tid >> 6;

    __shared__ float wsm[NR];
    __shared__ float red[4];
    __shared__ f32x4 part[4][64];

    float s = scores[b * NR + tid];
    float mx = s;
    #pragma unroll
    for (int d = 1; d < 64; d <<= 1) mx = fmaxf(mx, __shfl_xor(mx, d));
    if (lane == 0) red[wv] = mx;
    __syncthreads();
    mx = fmaxf(fmaxf(red[0], red[1]), fmaxf(red[2], red[3]));
    float e = __expf(s - mx);
    float sum = e;
    #pragma unroll
    for (int d = 1; d < 64; d <<= 1) sum += __shfl_xor(sum, d);
    __syncthreads();
    if (lane == 0) red[wv] = sum;
    __syncthreads();
    sum = red[0] + red[1] + red[2] + red[3];
    float w = e * (1.f / sum);
    wsm[tid] = w;
    if (chunk == 0) out[(size_t)NB * VIS_DIM + b * NR + tid] = w;
    __syncthreads();

    const float* vb = visual + ((size_t)b * NR + wv * 64) * VIS_DIM + chunk * 256 + lane * 4;
    f32x4 acc = {0.f, 0.f, 0.f, 0.f};
    #pragma unroll
    for (int r = 0; r < 64; r += 4) {
        f32x4 v0 = *(const f32x4*)(vb + (size_t)(r + 0) * VIS_DIM);
        f32x4 v1 = *(const f32x4*)(vb + (size_t)(r + 1) * VIS_DIM);
        f32x4 v2 = *(const f32x4*)(vb + (size_t)(r + 2) * VIS_DIM);
        f32x4 v3 = *(const f32x4*)(vb + (size_t)(r + 3) * VIS_DIM);
        acc += wsm[wv * 64 + r + 0] * v0;
        acc += wsm[wv * 64 + r + 1] * v1;
        acc += wsm[wv * 64 + r + 2] * v2;
        acc += wsm[wv * 64 + r + 3] * v3;
    }
    part[wv][lane] = acc;
    __syncthreads();
    if (wv == 0) {
        f32x4 a = part[0][lane] + part[1][lane] + part[2][lane] + part[3][lane];
        *(f32x4*)(out + (size_t)b * VIS_DIM + chunk * 256 + lane * 4) = a;
    }
}

// ---------------------------------------------------------------------------
extern "C" void kernel_launch(void* const* d_in, const int* in_sizes, int n_in,
                              void* d_out, int out_size, void* d_ws, size_t ws_size,
                              hipStream_t stream) {
    (void)in_sizes; (void)n_in; (void)out_size; (void)ws_size;
    const float* visual = (const float*)d_in[0];
    const float* text   = (const float*)d_in[1];
    const float* Wv     = (const float*)d_in[2];
    const float* bv     = (const float*)d_in[3];
    const float* Wt     = (const float*)d_in[4];
    const float* bt     = (const float*)d_in[5];
    const float* Wa     = (const float*)d_in[6];
    // d_in[7] = ba : softmax-shift-invariant, unused.

    float* out    = (float*)d_out;
    float* scores = (float*)d_ws;          // 32768 f32
    float* tbuf   = scores + M_TOT;        // 131072 f32  (total ws use: 640 KiB)

    init_ws  <<<512, 256, 0, stream>>>(scores, tbuf, bt);
    gemm_text<<<dim3(32, 4), 256, 0, stream>>>(text, Wt, tbuf);
    gemm_vis <<<2048, 256, 0, stream>>>(visual, Wv, bv, Wa, tbuf, scores);
    attend   <<<dim3(8, NB), 256, 0, stream>>>(visual, scores, out);
}

// Round 9
// 349.585 us; speedup vs baseline: 1.0516x; 1.0516x over previous
//
#include <hip/hip_runtime.h>
#include <hip/hip_bf16.h>

#define VIS_DIM 2048
#define TXT_DIM 1024
#define HID     1024
#define NB      128          // batch
#define NR      256          // regions
#define M_TOT   (NB*NR)      // 32768

typedef __attribute__((ext_vector_type(4))) float  f32x4;
typedef __attribute__((ext_vector_type(8))) short  short8;   // 8 x bf16 (4 VGPR)
typedef __attribute__((ext_vector_type(4))) unsigned short u16x4;

static __device__ __forceinline__ unsigned short f2bf(float f) {
    union { __hip_bfloat16 h; unsigned short u; } c;
    c.h = __float2bfloat16(f);
    return c.u;
}

static __device__ __forceinline__ float tanh_fast(float x) {
    float xc = fminf(fmaxf(x, -15.f), 15.f);
    float e  = __expf(2.f * xc);
    return (e - 1.f) / (e + 1.f);
}

// ---------------------------------------------------------------------------
// init: zero scores, t = bt broadcast (atomics accumulate on top)
// ---------------------------------------------------------------------------
__global__ void init_ws(float* __restrict__ scores, float* __restrict__ tbuf,
                        const float* __restrict__ bt) {
    int i = blockIdx.x * 256 + threadIdx.x;        // grid covers 131072
    if (i < M_TOT) scores[i] = 0.f;
    tbuf[i] = bt[i & (HID - 1)];
}

// ---------------------------------------------------------------------------
// t = text @ Wt^T (+bt already in tbuf). Split-K fp32 tiled GEMM, atomicAdd.
// ---------------------------------------------------------------------------
__global__ __launch_bounds__(256) void gemm_text(const float* __restrict__ text,
                                                 const float* __restrict__ Wt,
                                                 float* __restrict__ tbuf) {
    __shared__ float As[128][33];
    __shared__ float Bs[32][33];
    const int n0  = blockIdx.x * 32;
    const int k0  = blockIdx.y * 256;
    const int tid = threadIdx.x;
    const int tm  = tid >> 3;
    const int tn  = tid & 7;
    float acc[4][4] = {};
    for (int kt = 0; kt < 8; ++kt) {
        const int k = k0 + kt * 32;
        {   // stage A: 128x32
            int row = tid >> 1, off = (tid & 1) * 16;
            const float* src = text + row * TXT_DIM + k + off;
            #pragma unroll
            for (int j = 0; j < 4; ++j) {
                f32x4 v = *(const f32x4*)(src + j * 4);
                As[row][off + j*4 + 0] = v.x; As[row][off + j*4 + 1] = v.y;
                As[row][off + j*4 + 2] = v.z; As[row][off + j*4 + 3] = v.w;
            }
        }
        {   // stage B: 32x32
            int row = tid >> 3, off = (tid & 7) * 4;
            f32x4 v = *(const f32x4*)(Wt + (size_t)(n0 + row) * TXT_DIM + k + off);
            Bs[row][off + 0] = v.x; Bs[row][off + 1] = v.y;
            Bs[row][off + 2] = v.z; Bs[row][off + 3] = v.w;
        }
        __syncthreads();
        #pragma unroll
        for (int kk = 0; kk < 32; ++kk) {
            float a[4], b[4];
            #pragma unroll
            for (int i = 0; i < 4; ++i) a[i] = As[tm*4 + i][kk];
            #pragma unroll
            for (int j = 0; j < 4; ++j) b[j] = Bs[tn*4 + j][kk];
            #pragma unroll
            for (int i = 0; i < 4; ++i)
                #pragma unroll
                for (int j = 0; j < 4; ++j) acc[i][j] += a[i] * b[j];
        }
        __syncthreads();
    }
    #pragma unroll
    for (int i = 0; i < 4; ++i)
        #pragma unroll
        for (int j = 0; j < 4; ++j)
            atomicAdd(&tbuf[(tm*4 + i) * HID + n0 + tn*4 + j], acc[i][j]);
}

// ---------------------------------------------------------------------------
// Main fused GEMM: scores[row] += sum_col Wa[col]*tanh(A@Wv^T + bv + t)
// R9: 128x256 tile, 8 waves (wave tile 64x64 -> acc stays 64 VGPR).
//  - B staged via global_load_lds fp32 (ZERO stage regs), double-buffered
//    2x32KB LDS, source pre-swizzled (slot ^= row&7) for conflict-free
//    fragment reads; bf16 cvt at fragment-load time.
//  - A reg-staged depth-2 (2 loads/thread/set = 16 VGPR total) to bf16 LDS.
//  - Budget ~120-128 VGPR @ launch_bounds(512,4) -> 2 blocks x 8 waves =
//    16 waves/CU (50%); LDS 80KB -> exactly 2 blocks; grid 1024 = exactly
//    2 rounds, zero tail. (128^2: acc64+stage64 could never fit 128.)
//  - Raw s_barrier + counted vmcnt (the __syncthreads vmcnt(0) drain would
//    kill the pipeline). Issue order B(t+1),A(t+2) -> VWAIT(2) keeps A(t+2)
//    in flight (age 2 iters ~ HBM); B age 1 iter covers L2-hit (each XCD
//    owns one 2MB B panel under wg%8 round-robin: nb = wg&3).
//  - VMEM aggregate 4GB -> 3GB (A read 4x not 8x).
// ---------------------------------------------------------------------------
#define BK 32
#define NT (VIS_DIM / BK)    // 64

// byte offset inside the 8 KB bf16 A tile [128 rows][32 k], 16B-slot swizzled
// (row stride 64 B: row bit0 is addr bit6, so XOR uses (row>>1)&3)
static __device__ __forceinline__ int tile_off(int row, int kElem) {
    return row * 64 + (((kElem >> 3) ^ ((row >> 1) & 3)) << 4);
}

__global__ __launch_bounds__(512, 4) void gemm_vis(
        const float* __restrict__ A,     // visual  32768 x 2048
        const float* __restrict__ Bv,    // Wv      1024 x 2048
        const float* __restrict__ bv,
        const float* __restrict__ wa,    // Wa[0]   1024
        const float* __restrict__ tbuf,  // 128 x 1024
        float* __restrict__ scores) {
    // [0,16384): A bf16 tiles, 2 x 8KB.  [16384,81920): B fp32 tiles, 2 x 32KB.
    __shared__ __align__(16) char lds[81920];

    const int wg   = blockIdx.x;        // 1024 = 256 mb x 4 nb, nb fastest
    const int nb   = wg & 3;
    const int mb   = wg >> 2;
    const int brow = mb * 128;
    const int bcol = nb * 256;

    const int tid  = threadIdx.x;       // 512 threads
    const int lane = tid & 63;
    const int wid  = tid >> 6;          // 0..7
    const int wr   = wid >> 2;          // 0..1  (2 x 4 wave grid)
    const int wc   = wid & 3;           // 0..3

    // ---- A staging map: 2 loads/thread: rows (tid>>3), +64; sfs = tid&7
    const int rowA0 = tid >> 3;         // 0..63
    const int sfsA  = tid & 7;
    unsigned vaA = ((unsigned)(brow + rowA0) * VIS_DIM + sfsA * 4) * 4u;
    const int wbyteA = rowA0 * 64 +
        (((sfsA >> 1) ^ ((rowA0 >> 1) & 3)) << 4) + (sfsA & 1) * 8;
    // row+64: (row>>1)&3 unchanged -> wbyte just +64*64 = +4096

    // ---- B gload_lds map: wave w, instr j covers rows 64j+8w .. +7.
    // lane: row = 64j+8w+(lane>>3); src slot = (lane&7) ^ ((lane>>3)&7)
    // (pre-swizzle so LDS[r][s] = G[r][s^(r&7)] with LINEAR lds dest).
    const int rowB0   = 8 * wid + (lane >> 3);
    const int srcslot = (lane & 7) ^ ((lane >> 3) & 7);
    const float* pB = Bv + (size_t)(bcol + rowB0) * VIS_DIM + srcslot * 4;
    __attribute__((address_space(3))) char* ldsB3 =
        (__attribute__((address_space(3))) char*)(lds + 16384);
    const int wslot = wid * 1024;

    f32x4 sA0, sA1, tA0, tA1;           // A stage sets S, T (16 VGPR)
    f32x4 acc[4][4] = {};

#define GLOAD_A(d0, d1)                                                        \
    do {                                                                       \
        asm volatile("global_load_dwordx4 %0, %1, %2"                          \
                     : "=&v"(d0) : "v"(vaA), "s"(A) : "memory");               \
        asm volatile("global_load_dwordx4 %0, %1, %2"                          \
                     : "=&v"(d1) : "v"(vaA + 524288u), "s"(A) : "memory");     \
        vaA += 128u;                                                           \
    } while (0)

#define GLOADB(c)                                                              \
    do {                                                                       \
        _Pragma("unroll")                                                      \
        for (int j_ = 0; j_ < 4; ++j_)                                         \
            __builtin_amdgcn_global_load_lds(                                  \
                (const __attribute__((address_space(1))) float*)(pB + j_ * 131072), \
                (__attribute__((address_space(3))) float*)(ldsB3 + (c) * 32768 + wslot + j_ * 8192), \
                16, 0, 0);                                                     \
        pB += BK;                                                              \
    } while (0)

#define VWAIT(N)                                                               \
    do {                                                                       \
        __builtin_amdgcn_sched_barrier(0);                                     \
        asm volatile("s_waitcnt vmcnt(" #N ")" ::: "memory");                  \
        __builtin_amdgcn_sched_barrier(0);                                     \
    } while (0)

    // raw barrier: counted vmcnt stays in flight; drain only LDS ops
#define BARRIER()                                                              \
    do {                                                                       \
        __builtin_amdgcn_sched_barrier(0);                                     \
        asm volatile("s_waitcnt lgkmcnt(0)" ::: "memory");                     \
        __builtin_amdgcn_s_barrier();                                          \
        __builtin_amdgcn_sched_barrier(0);                                     \
    } while (0)

#define CVT8(dst, v0)                                                          \
    do {                                                                       \
        u16x4 t_;                                                              \
        t_.x = f2bf((v0).x); t_.y = f2bf((v0).y);                              \
        t_.z = f2bf((v0).z); t_.w = f2bf((v0).w);                              \
        dst = t_;                                                              \
    } while (0)

#define LWRITE_A(c, d0, d1)                                                    \
    do {                                                                       \
        u16x4 w_;                                                              \
        char* la = lds + (c) * 8192;                                           \
        CVT8(w_, d0); *(u16x4*)(la + wbyteA) = w_;                             \
        CVT8(w_, d1); *(u16x4*)(la + wbyteA + 4096) = w_;                      \
    } while (0)

#define COMPUTE(c)                                                             \
    do {                                                                       \
        const char* laA = lds + (c) * 8192;                                    \
        const char* laB = lds + 16384 + (c) * 32768;                           \
        short8 bfr[4];                                                         \
        const int g_ = lane >> 4, l_ = lane & 15;                              \
        _Pragma("unroll")                                                      \
        for (int n = 0; n < 4; ++n) {                                          \
            int r_ = wc * 64 + n * 16 + l_;                                    \
            int x_ = r_ & 7;                                                   \
            f32x4 lo = *(const f32x4*)(laB + r_ * 128 + (((2 * g_)     ^ x_) << 4)); \
            f32x4 hi = *(const f32x4*)(laB + r_ * 128 + (((2 * g_ + 1) ^ x_) << 4)); \
            short8 t_;                                                         \
            t_[0] = (short)f2bf(lo.x); t_[1] = (short)f2bf(lo.y);              \
            t_[2] = (short)f2bf(lo.z); t_[3] = (short)f2bf(lo.w);              \
            t_[4] = (short)f2bf(hi.x); t_[5] = (short)f2bf(hi.y);              \
            t_[6] = (short)f2bf(hi.z); t_[7] = (short)f2bf(hi.w);              \
            bfr[n] = t_;                                                       \
        }                                                                      \
        _Pragma("unroll")                                                      \
        for (int m = 0; m < 4; ++m) {                                          \
            int rA_ = wr * 64 + m * 16 + l_;                                   \
            short8 af = *(const short8*)(laA + tile_off(rA_, g_ * 8));         \
            acc[m][0] = __builtin_amdgcn_mfma_f32_16x16x32_bf16(af, bfr[0], acc[m][0], 0, 0, 0); \
            acc[m][1] = __builtin_amdgcn_mfma_f32_16x16x32_bf16(af, bfr[1], acc[m][1], 0, 0, 0); \
            acc[m][2] = __builtin_amdgcn_mfma_f32_16x16x32_bf16(af, bfr[2], acc[m][2], 0, 0, 0); \
            acc[m][3] = __builtin_amdgcn_mfma_f32_16x16x32_bf16(af, bfr[3], acc[m][3], 0, 0, 0); \
        }                                                                      \
    } while (0)

    // ---- Prologue: B(0)->bufB0, A(0)->S, A(1)->T; stage tile 0.
    GLOADB(0);                  // B(0)  [4 out]
    __builtin_amdgcn_sched_barrier(0);
    GLOAD_A(sA0, sA1);          // A(0)  [6]
    GLOAD_A(tA0, tA1);          // A(1)  [8]
    VWAIT(2);                   // B(0)+A(0) done; A(1) in flight
    LWRITE_A(0, sA0, sA1);      // A(0) -> bufA0
    BARRIER();

    // ---- Main loop: t = 0..61 as 31 unrolled pairs.
    // Invariant at pair top: buf(t&1)=buf0 valid; outstanding = A(t+1) [2].
    #pragma unroll 1
    for (int it = 0; it < 31; ++it) {
        // even t (buf0): B(t+1)->bufB1 (readers of buf1 done at last barrier),
        // A(t+2)->S; compute; drain A(t+1)+B(t+1); write A(t+1)->bufA1.
        GLOADB(1);
        __builtin_amdgcn_sched_barrier(0);
        GLOAD_A(sA0, sA1);
        __builtin_amdgcn_sched_barrier(0);
        COMPUTE(0);
        VWAIT(2);               // FIFO: [A(t+1), B(t+1), A(t+2)] -> keep A(t+2)
        LWRITE_A(1, tA0, tA1);
        BARRIER();
        // odd t+1 (buf1): B(t+2)->bufB0, A(t+3)->T; write A(t+2)->bufA0.
        GLOADB(0);
        __builtin_amdgcn_sched_barrier(0);
        GLOAD_A(tA0, tA1);
        __builtin_amdgcn_sched_barrier(0);
        COMPUTE(1);
        VWAIT(2);
        LWRITE_A(0, sA0, sA1);
        BARRIER();
    }
    // ---- Tail: t=62 (buf0): B(63)->bufB1; outstanding A(63) in T.
    GLOADB(1);
    __builtin_amdgcn_sched_barrier(0);
    COMPUTE(0);
    VWAIT(0);                   // drain A(63)+B(63)
    LWRITE_A(1, tA0, tA1);
    BARRIER();
    COMPUTE(1);                 // t=63
#undef GLOAD_A
#undef GLOADB
#undef VWAIT
#undef BARRIER
#undef CVT8
#undef LWRITE_A
#undef COMPUTE

    // ---- epilogue: tanh + Wa-dot, reduce over 16 cols/lane-group, atomicAdd
    const int b = brow >> 8;                 // batch index (tile fits in one b)
    float wa_c[4], bvt_c[4];
    #pragma unroll
    for (int n = 0; n < 4; ++n) {
        int col = bcol + wc * 64 + n * 16 + (lane & 15);
        wa_c[n]  = wa[col];
        bvt_c[n] = bv[col] + tbuf[b * HID + col];
    }
    #pragma unroll
    for (int m = 0; m < 4; ++m) {
        float p0 = 0.f, p1 = 0.f, p2 = 0.f, p3 = 0.f;
        #pragma unroll
        for (int n = 0; n < 4; ++n) {
            f32x4 v = acc[m][n];
            p0 += wa_c[n] * tanh_fast(v.x + bvt_c[n]);
            p1 += wa_c[n] * tanh_fast(v.y + bvt_c[n]);
            p2 += wa_c[n] * tanh_fast(v.z + bvt_c[n]);
            p3 += wa_c[n] * tanh_fast(v.w + bvt_c[n]);
        }
        #pragma unroll
        for (int d = 1; d < 16; d <<= 1) {
            p0 += __shfl_xor(p0, d); p1 += __shfl_xor(p1, d);
            p2 += __shfl_xor(p2, d); p3 += __shfl_xor(p3, d);
        }
        if ((lane & 15) == 0) {
            int rowg = brow + wr * 64 + m * 16 + (lane >> 4) * 4;
            atomicAdd(&scores[rowg + 0], p0);
            atomicAdd(&scores[rowg + 1], p1);
            atomicAdd(&scores[rowg + 2], p2);
            atomicAdd(&scores[rowg + 3], p3);
        }
    }
}

// ---------------------------------------------------------------------------
// softmax over regions + attended = w . visual ; grid (8 d-chunks, 128 b)
// ---------------------------------------------------------------------------
__global__ __launch_bounds__(256) void attend(const float* __restrict__ visual,
                                              const float* __restrict__ scores,
                                              float* __restrict__ out) {
    const int chunk = blockIdx.x;   // 0..7 -> 256 d each
    const int b     = blockIdx.y;   // 0..127
    const int tid   = threadIdx.x;
    const int lane  = tid & 63;
    const int wv    = tid >> 6;

    __shared__ float wsm[NR];
    __shared__ float red[4];
    __shared__ f32x4 part[4][64];

    float s = scores[b * NR + tid];
    float mx = s;
    #pragma unroll
    for (int d = 1; d < 64; d <<= 1) mx = fmaxf(mx, __shfl_xor(mx, d));
    if (lane == 0) red[wv] = mx;
    __syncthreads();
    mx = fmaxf(fmaxf(red[0], red[1]), fmaxf(red[2], red[3]));
    float e = __expf(s - mx);
    float sum = e;
    #pragma unroll
    for (int d = 1; d < 64; d <<= 1) sum += __shfl_xor(sum, d);
    __syncthreads();
    if (lane == 0) red[wv] = sum;
    __syncthreads();
    sum = red[0] + red[1] + red[2] + red[3];
    float w = e * (1.f / sum);
    wsm[tid] = w;
    if (chunk == 0) out[(size_t)NB * VIS_DIM + b * NR + tid] = w;
    __syncthreads();

    const float* vb = visual + ((size_t)b * NR + wv * 64) * VIS_DIM + chunk * 256 + lane * 4;
    f32x4 acc = {0.f, 0.f, 0.f, 0.f};
    #pragma unroll
    for (int r = 0; r < 64; r += 4) {
        f32x4 v0 = *(const f32x4*)(vb + (size_t)(r + 0) * VIS_DIM);
        f32x4 v1 = *(const f32x4*)(vb + (size_t)(r + 1) * VIS_DIM);
        f32x4 v2 = *(const f32x4*)(vb + (size_t)(r + 2) * VIS_DIM);
        f32x4 v3 = *(const f32x4*)(vb + (size_t)(r + 3) * VIS_DIM);
        acc += wsm[wv * 64 + r + 0] * v0;
        acc += wsm[wv * 64 + r + 1] * v1;
        acc += wsm[wv * 64 + r + 2] * v2;
        acc += wsm[wv * 64 + r + 3] * v3;
    }
    part[wv][lane] = acc;
    __syncthreads();
    if (wv == 0) {
        f32x4 a = part[0][lane] + part[1][lane] + part[2][lane] + part[3][lane];
        *(f32x4*)(out + (size_t)b * VIS_DIM + chunk * 256 + lane * 4) = a;
    }
}

// ---------------------------------------------------------------------------
extern "C" void kernel_launch(void* const* d_in, const int* in_sizes, int n_in,
                              void* d_out, int out_size, void* d_ws, size_t ws_size,
                              hipStream_t stream) {
    (void)in_sizes; (void)n_in; (void)out_size; (void)ws_size;
    const float* visual = (const float*)d_in[0];
    const float* text   = (const float*)d_in[1];
    const float* Wv     = (const float*)d_in[2];
    const float* bv     = (const float*)d_in[3];
    const float* Wt     = (const float*)d_in[4];
    const float* bt     = (const float*)d_in[5];
    const float* Wa     = (const float*)d_in[6];
    // d_in[7] = ba : softmax-shift-invariant, unused.

    float* out    = (float*)d_out;
    float* scores = (float*)d_ws;          // 32768 f32
    float* tbuf   = scores + M_TOT;        // 131072 f32  (total ws use: 640 KiB)

    init_ws  <<<512, 256, 0, stream>>>(scores, tbuf, bt);
    gemm_text<<<dim3(32, 4), 256, 0, stream>>>(text, Wt, tbuf);
    gemm_vis <<<1024, 512, 0, stream>>>(visual, Wv, bv, Wa, tbuf, scores);
    attend   <<<dim3(8, NB), 256, 0, stream>>>(visual, scores, out);
}

// Round 10
// 280.635 us; speedup vs baseline: 1.3099x; 1.2457x over previous
//
#include <hip/hip_runtime.h>
#include <hip/hip_bf16.h>

#define VIS_DIM 2048
#define TXT_DIM 1024
#define HID     1024
#define NB      128          // batch
#define NR      256          // regions
#define M_TOT   (NB*NR)      // 32768

typedef __attribute__((ext_vector_type(4))) float  f32x4;
typedef __attribute__((ext_vector_type(8))) short  short8;   // 8 x bf16 (4 VGPR)
typedef __attribute__((ext_vector_type(4))) unsigned short u16x4;

static __device__ __forceinline__ unsigned short f2bf(float f) {
    union { __hip_bfloat16 h; unsigned short u; } c;
    c.h = __float2bfloat16(f);
    return c.u;
}

static __device__ __forceinline__ float tanh_fast(float x) {
    float xc = fminf(fmaxf(x, -15.f), 15.f);
    float e  = __expf(2.f * xc);
    return (e - 1.f) / (e + 1.f);
}

// ---------------------------------------------------------------------------
// init: zero scores, t = bt broadcast (atomics accumulate on top)
// ---------------------------------------------------------------------------
__global__ void init_ws(float* __restrict__ scores, float* __restrict__ tbuf,
                        const float* __restrict__ bt) {
    int i = blockIdx.x * 256 + threadIdx.x;        // grid covers 131072
    if (i < M_TOT) scores[i] = 0.f;
    tbuf[i] = bt[i & (HID - 1)];
}

// ---------------------------------------------------------------------------
// t = text @ Wt^T (+bt already in tbuf). Split-K fp32 tiled GEMM, atomicAdd.
// ---------------------------------------------------------------------------
__global__ __launch_bounds__(256) void gemm_text(const float* __restrict__ text,
                                                 const float* __restrict__ Wt,
                                                 float* __restrict__ tbuf) {
    __shared__ float As[128][33];
    __shared__ float Bs[32][33];
    const int n0  = blockIdx.x * 32;
    const int k0  = blockIdx.y * 256;
    const int tid = threadIdx.x;
    const int tm  = tid >> 3;
    const int tn  = tid & 7;
    float acc[4][4] = {};
    for (int kt = 0; kt < 8; ++kt) {
        const int k = k0 + kt * 32;
        {   // stage A: 128x32
            int row = tid >> 1, off = (tid & 1) * 16;
            const float* src = text + row * TXT_DIM + k + off;
            #pragma unroll
            for (int j = 0; j < 4; ++j) {
                f32x4 v = *(const f32x4*)(src + j * 4);
                As[row][off + j*4 + 0] = v.x; As[row][off + j*4 + 1] = v.y;
                As[row][off + j*4 + 2] = v.z; As[row][off + j*4 + 3] = v.w;
            }
        }
        {   // stage B: 32x32
            int row = tid >> 3, off = (tid & 7) * 4;
            f32x4 v = *(const f32x4*)(Wt + (size_t)(n0 + row) * TXT_DIM + k + off);
            Bs[row][off + 0] = v.x; Bs[row][off + 1] = v.y;
            Bs[row][off + 2] = v.z; Bs[row][off + 3] = v.w;
        }
        __syncthreads();
        #pragma unroll
        for (int kk = 0; kk < 32; ++kk) {
            float a[4], b[4];
            #pragma unroll
            for (int i = 0; i < 4; ++i) a[i] = As[tm*4 + i][kk];
            #pragma unroll
            for (int j = 0; j < 4; ++j) b[j] = Bs[tn*4 + j][kk];
            #pragma unroll
            for (int i = 0; i < 4; ++i)
                #pragma unroll
                for (int j = 0; j < 4; ++j) acc[i][j] += a[i] * b[j];
        }
        __syncthreads();
    }
    #pragma unroll
    for (int i = 0; i < 4; ++i)
        #pragma unroll
        for (int j = 0; j < 4; ++j)
            atomicAdd(&tbuf[(tm*4 + i) * HID + n0 + tn*4 + j], acc[i][j]);
}

// ---------------------------------------------------------------------------
// Main fused GEMM: scores[row] += sum_col Wa[col]*tanh(A@Wv^T + bv + t)
// R10 = R5 structure with RAW BARRIERS. Root-cause found by R5-vs-R9 diff:
// __syncthreads() emits s_waitcnt vmcnt(0) lgkmcnt(0) before s_barrier, so
// every counted-vmcnt prefetch in R4-R8 was force-drained at each barrier --
// the depth-2/3 pipelines never existed on HW (invariant ~285us, ~1300cy/iter
// = compute + exposed HBM tail). R9 proved raw s_barrier + lgkmcnt(0)-only
// is correct here: cross-barrier loads target REGISTERS (not LDS), invisible
// to other waves, drained by the next VWAIT(8) before use; ds_writes are
// drained by lgkmcnt(0) before the barrier.
// ---------------------------------------------------------------------------
#define BK 32
#define NT (VIS_DIM / BK)    // 64

// byte offset inside one 8 KB bf16 tile [128 rows][32 k], 16B-slot swizzled
// (row stride 64 B: row bit0 is addr bit6, so XOR uses (row>>1)&3)
static __device__ __forceinline__ int tile_off(int row, int kElem) {
    return row * 64 + (((kElem >> 3) ^ ((row >> 1) & 3)) << 4);
}

__global__ __launch_bounds__(256, 2) void gemm_vis(
        const float* __restrict__ A,     // visual  32768 x 2048
        const float* __restrict__ Bv,    // Wv      1024 x 2048
        const float* __restrict__ bv,
        const float* __restrict__ wa,    // Wa[0]   1024
        const float* __restrict__ tbuf,  // 128 x 1024
        float* __restrict__ scores) {
    __shared__ __align__(16) char lds[32768];   // 2 buf x (A 8KB + B 8KB)

    // XCD-chunked mapping: xcd = wg&7 (HW round-robin), each XCD walks its
    // 256 local blocks n-fastest so nb=0..7 siblings of one mb are adjacent.
    const int wg   = blockIdx.x;
    const int xcd  = wg & 7;
    const int loc  = wg >> 3;               // 0..255
    const int mb   = xcd * 32 + (loc >> 3); // 0..255
    const int nb   = loc & 7;               // 0..7
    const int brow = mb * 128;
    const int bcol = nb * 128;

    const int tid  = threadIdx.x;
    const int lane = tid & 63;
    const int wid  = tid >> 6;
    const int wr   = wid >> 1, wc = wid & 1;   // 2x2 waves of 64x64

    // staging map: load r (0..3): row = (tid>>3)+32r, sfs = tid&7 (f32x4 slot)
    const int srow = tid >> 3;
    const int sfs  = tid & 7;
    // 32-bit byte voffsets into A / Bv (max 256 MB / 8 MB: fits u32)
    unsigned va0 = ((unsigned)(brow + srow      ) * VIS_DIM + sfs * 4) * 4u;
    unsigned va1 = va0 + 32u * VIS_DIM * 4u;
    unsigned va2 = va0 + 64u * VIS_DIM * 4u;
    unsigned va3 = va0 + 96u * VIS_DIM * 4u;
    unsigned vb0 = ((unsigned)(bcol + srow      ) * VIS_DIM + sfs * 4) * 4u;
    unsigned vb1 = vb0 + 32u * VIS_DIM * 4u;
    unsigned vb2 = vb0 + 64u * VIS_DIM * 4u;
    unsigned vb3 = vb0 + 96u * VIS_DIM * 4u;

    // LDS write byte offsets (within a tile) per r: 8B granule, swizzled
    int wbyte[4];
    #pragma unroll
    for (int r = 0; r < 4; ++r) {
        int row = srow + 32 * r;
        wbyte[r] = row * 64 + (((sfs >> 1) ^ ((row >> 1) & 3)) << 4) + (sfs & 1) * 8;
    }

    // Two stage sets: S (even tiles' loader) and T (odd tiles' loader).
    f32x4 sA0, sA1, sA2, sA3, sB0, sB1, sB2, sB3;
    f32x4 tA0, tA1, tA2, tA3, tB0, tB1, tB2, tB3;
    f32x4 acc[4][4] = {};

    // Issue 8 loads into a named set (volatile asm: pinned, un-spillable,
    // un-sinkable) and advance the shared offsets by one tile (128 B).
#define GLOAD_SET(dA0,dA1,dA2,dA3,dB0,dB1,dB2,dB3)                             \
    do {                                                                       \
        asm volatile("global_load_dwordx4 %0, %1, %2"                          \
                     : "=&v"(dA0) : "v"(va0), "s"(A) : "memory");              \
        asm volatile("global_load_dwordx4 %0, %1, %2"                          \
                     : "=&v"(dA1) : "v"(va1), "s"(A) : "memory");              \
        asm volatile("global_load_dwordx4 %0, %1, %2"                          \
                     : "=&v"(dA2) : "v"(va2), "s"(A) : "memory");              \
        asm volatile("global_load_dwordx4 %0, %1, %2"                          \
                     : "=&v"(dA3) : "v"(va3), "s"(A) : "memory");              \
        asm volatile("global_load_dwordx4 %0, %1, %2"                          \
                     : "=&v"(dB0) : "v"(vb0), "s"(Bv) : "memory");             \
        asm volatile("global_load_dwordx4 %0, %1, %2"                          \
                     : "=&v"(dB1) : "v"(vb1), "s"(Bv) : "memory");             \
        asm volatile("global_load_dwordx4 %0, %1, %2"                          \
                     : "=&v"(dB2) : "v"(vb2), "s"(Bv) : "memory");             \
        asm volatile("global_load_dwordx4 %0, %1, %2"                          \
                     : "=&v"(dB3) : "v"(vb3), "s"(Bv) : "memory");             \
        va0 += BK * 4; va1 += BK * 4; va2 += BK * 4; va3 += BK * 4;            \
        vb0 += BK * 4; vb1 += BK * 4; vb2 += BK * 4; vb3 += BK * 4;            \
    } while (0)

#define GLOAD_S() GLOAD_SET(sA0,sA1,sA2,sA3,sB0,sB1,sB2,sB3)
#define GLOAD_T() GLOAD_SET(tA0,tA1,tA2,tA3,tB0,tB1,tB2,tB3)

    // Counted wait: keep N newest loads in flight; fence compiler motion
    // (rule #18: register-only ops can hoist past asm waitcnt without the
    // sched_barrier pair).
#define VWAIT(N)                                                               \
    do {                                                                       \
        __builtin_amdgcn_sched_barrier(0);                                     \
        asm volatile("s_waitcnt vmcnt(" #N ")" ::: "memory");                  \
        __builtin_amdgcn_sched_barrier(0);                                     \
    } while (0)

    // RAW barrier: drain only LDS ops (ds_writes must be visible), leave the
    // counted global-load prefetch IN FLIGHT across the barrier. This is the
    // whole point of R10 -- __syncthreads() would drain vmcnt(0) too.
#define BARRIER()                                                              \
    do {                                                                       \
        __builtin_amdgcn_sched_barrier(0);                                     \
        asm volatile("s_waitcnt lgkmcnt(0)" ::: "memory");                     \
        __builtin_amdgcn_s_barrier();                                          \
        __builtin_amdgcn_sched_barrier(0);                                     \
    } while (0)

#define CVT8(dst, v0)                                                          \
    do {                                                                       \
        u16x4 t_;                                                              \
        t_.x = f2bf((v0).x); t_.y = f2bf((v0).y);                              \
        t_.z = f2bf((v0).z); t_.w = f2bf((v0).w);                              \
        dst = t_;                                                              \
    } while (0)

#define LWRITE_SET(bufbase, dA0,dA1,dA2,dA3,dB0,dB1,dB2,dB3)                   \
    do {                                                                       \
        u16x4 w_;                                                              \
        char* la = lds + (bufbase);                                            \
        char* lb = lds + (bufbase) + 8192;                                     \
        CVT8(w_, dA0); *(u16x4*)(la + wbyte[0]) = w_;                          \
        CVT8(w_, dA1); *(u16x4*)(la + wbyte[1]) = w_;                          \
        CVT8(w_, dA2); *(u16x4*)(la + wbyte[2]) = w_;                          \
        CVT8(w_, dA3); *(u16x4*)(la + wbyte[3]) = w_;                          \
        CVT8(w_, dB0); *(u16x4*)(lb + wbyte[0]) = w_;                          \
        CVT8(w_, dB1); *(u16x4*)(lb + wbyte[1]) = w_;                          \
        CVT8(w_, dB2); *(u16x4*)(lb + wbyte[2]) = w_;                          \
        CVT8(w_, dB3); *(u16x4*)(lb + wbyte[3]) = w_;                          \
    } while (0)

#define LWRITE_S(bufbase) LWRITE_SET(bufbase, sA0,sA1,sA2,sA3,sB0,sB1,sB2,sB3)
#define LWRITE_T(bufbase) LWRITE_SET(bufbase, tA0,tA1,tA2,tA3,tB0,tB1,tB2,tB3)

#define COMPUTE(bufbase)                                                       \
    do {                                                                       \
        short8 af[4], bf[4];                                                   \
        const int kk = (lane >> 4) * 8;                                        \
        const char* la = lds + (bufbase);                                      \
        const char* lb = lds + (bufbase) + 8192;                               \
        _Pragma("unroll")                                                      \
        for (int m = 0; m < 4; ++m)                                            \
            af[m] = *(const short8*)(la + tile_off(wr*64 + m*16 + (lane&15), kk)); \
        _Pragma("unroll")                                                      \
        for (int n = 0; n < 4; ++n)                                            \
            bf[n] = *(const short8*)(lb + tile_off(wc*64 + n*16 + (lane&15), kk)); \
        _Pragma("unroll")                                                      \
        for (int m = 0; m < 4; ++m)                                            \
            _Pragma("unroll")                                                  \
            for (int n = 0; n < 4; ++n)                                        \
                acc[m][n] = __builtin_amdgcn_mfma_f32_16x16x32_bf16(           \
                    af[m], bf[n], acc[m][n], 0, 0, 0);                         \
    } while (0)

    // Prologue: tiles 0 (S) and 1 (T) issued; stage tile 0 into buf0.
    GLOAD_S();                 // tile 0  (outstanding 8)
    GLOAD_T();                 // tile 1  (outstanding 16)
    VWAIT(8);                  // S ready; T in flight
    LWRITE_S(0);
    BARRIER();                 // T's 8 loads stay in flight across it

    // Steady state: invariant at iter-top = 8 outstanding (next tile's batch).
    #pragma unroll 1
    for (int kt = 0; kt < NT - 2; kt += 2) {
        // even tile kt: buf0 compute, prefetch kt+2 into S, stage kt+1 (T)->buf1
        GLOAD_S();             // tile kt+2 (outstanding 16)
        COMPUTE(0);
        VWAIT(8);              // T (tile kt+1) ready; S stays in flight
        LWRITE_T(16384);
        BARRIER();             // S crosses the barrier un-drained
        // odd tile kt+1: buf1 compute, prefetch kt+3 into T, stage kt+2 (S)->buf0
        GLOAD_T();             // tile kt+3 (outstanding 16)
        COMPUTE(16384);
        VWAIT(8);              // S (tile kt+2) ready; T stays in flight
        LWRITE_S(0);
        BARRIER();
    }
    // Epilogue: buf0 holds tile 62; T's batch (tile 63) still in flight.
    COMPUTE(0);
    VWAIT(0);
    LWRITE_T(16384);
    BARRIER();
    COMPUTE(16384);
#undef GLOAD_SET
#undef GLOAD_S
#undef GLOAD_T
#undef VWAIT
#undef BARRIER
#undef CVT8
#undef LWRITE_SET
#undef LWRITE_S
#undef LWRITE_T
#undef COMPUTE

    // ---- epilogue: tanh + Wa-dot, reduce over 16 cols/lane-group, atomicAdd
    const int b = brow >> 8;                 // batch index (tile fits in one b)
    float wa_c[4], bvt_c[4];
    #pragma unroll
    for (int n = 0; n < 4; ++n) {
        int col = bcol + wc * 64 + n * 16 + (lane & 15);
        wa_c[n]  = wa[col];
        bvt_c[n] = bv[col] + tbuf[b * HID + col];
    }
    #pragma unroll
    for (int m = 0; m < 4; ++m) {
        float p0 = 0.f, p1 = 0.f, p2 = 0.f, p3 = 0.f;
        #pragma unroll
        for (int n = 0; n < 4; ++n) {
            f32x4 v = acc[m][n];
            p0 += wa_c[n] * tanh_fast(v.x + bvt_c[n]);
            p1 += wa_c[n] * tanh_fast(v.y + bvt_c[n]);
            p2 += wa_c[n] * tanh_fast(v.z + bvt_c[n]);
            p3 += wa_c[n] * tanh_fast(v.w + bvt_c[n]);
        }
        #pragma unroll
        for (int d = 1; d < 16; d <<= 1) {
            p0 += __shfl_xor(p0, d); p1 += __shfl_xor(p1, d);
            p2 += __shfl_xor(p2, d); p3 += __shfl_xor(p3, d);
        }
        if ((lane & 15) == 0) {
            int rowg = brow + wr * 64 + m * 16 + (lane >> 4) * 4;
            atomicAdd(&scores[rowg + 0], p0);
            atomicAdd(&scores[rowg + 1], p1);
            atomicAdd(&scores[rowg + 2], p2);
            atomicAdd(&scores[rowg + 3], p3);
        }
    }
}

// ---------------------------------------------------------------------------
// softmax over regions + attended = w . visual ; grid (8 d-chunks, 128 b)
// ---------------------------------------------------------------------------
__global__ __launch_bounds__(256) void attend(const float* __restrict__ visual,
                                              const float* __restrict__ scores,
                                              float* __restrict__ out) {
    const int chunk = blockIdx.x;   // 0..7 -> 256 d each
    const int b     = blockIdx.y;   // 0..127
    const int tid   = threadIdx.x;
    const int lane  = tid & 63;
    const int wv    = tid >> 6;

    __shared__ float wsm[NR];
    __shared__ float red[4];
    __shared__ f32x4 part[4][64];

    float s = scores[b * NR + tid];
    float mx = s;
    #pragma unroll
    for (int d = 1; d < 64; d <<= 1) mx = fmaxf(mx, __shfl_xor(mx, d));
    if (lane == 0) red[wv] = mx;
    __syncthreads();
    mx = fmaxf(fmaxf(red[0], red[1]), fmaxf(red[2], red[3]));
    float e = __expf(s - mx);
    float sum = e;
    #pragma unroll
    for (int d = 1; d < 64; d <<= 1) sum += __shfl_xor(sum, d);
    __syncthreads();
    if (lane == 0) red[wv] = sum;
    __syncthreads();
    sum = red[0] + red[1] + red[2] + red[3];
    float w = e * (1.f / sum);
    wsm[tid] = w;
    if (chunk == 0) out[(size_t)NB * VIS_DIM + b * NR + tid] = w;
    __syncthreads();

    const float* vb = visual + ((size_t)b * NR + wv * 64) * VIS_DIM + chunk * 256 + lane * 4;
    f32x4 acc = {0.f, 0.f, 0.f, 0.f};
    #pragma unroll
    for (int r = 0; r < 64; r += 4) {
        f32x4 v0 = *(const f32x4*)(vb + (size_t)(r + 0) * VIS_DIM);
        f32x4 v1 = *(const f32x4*)(vb + (size_t)(r + 1) * VIS_DIM);
        f32x4 v2 = *(const f32x4*)(vb + (size_t)(r + 2) * VIS_DIM);
        f32x4 v3 = *(const f32x4*)(vb + (size_t)(r + 3) * VIS_DIM);
        acc += wsm[wv * 64 + r + 0] * v0;
        acc += wsm[wv * 64 + r + 1] * v1;
        acc += wsm[wv * 64 + r + 2] * v2;
        acc += wsm[wv * 64 + r + 3] * v3;
    }
    part[wv][lane] = acc;
    __syncthreads();
    if (wv == 0) {
        f32x4 a = part[0][lane] + part[1][lane] + part[2][lane] + part[3][lane];
        *(f32x4*)(out + (size_t)b * VIS_DIM + chunk * 256 + lane * 4) = a;
    }
}

// ---------------------------------------------------------------------------
extern "C" void kernel_launch(void* const* d_in, const int* in_sizes, int n_in,
                              void* d_out, int out_size, void* d_ws, size_t ws_size,
                              hipStream_t stream) {
    (void)in_sizes; (void)n_in; (void)out_size; (void)ws_size;
    const float* visual = (const float*)d_in[0];
    const float* text   = (const float*)d_in[1];
    const float* Wv     = (const float*)d_in[2];
    const float* bv     = (const float*)d_in[3];
    const float* Wt     = (const float*)d_in[4];
    const float* bt     = (const float*)d_in[5];
    const float* Wa     = (const float*)d_in[6];
    // d_in[7] = ba : softmax-shift-invariant, unused.

    float* out    = (float*)d_out;
    float* scores = (float*)d_ws;          // 32768 f32
    float* tbuf   = scores + M_TOT;        // 131072 f32  (total ws use: 640 KiB)

    init_ws  <<<512, 256, 0, stream>>>(scores, tbuf, bt);
    gemm_text<<<dim3(32, 4), 256, 0, stream>>>(text, Wt, tbuf);
    gemm_vis <<<2048, 256, 0, stream>>>(visual, Wv, bv, Wa, tbuf, scores);
    attend   <<<dim3(8, NB), 256, 0, stream>>>(visual, scores, out);
}